// Round 7
// baseline (277.618 us; speedup 1.0000x reference)
//
#include <hip/hip_runtime.h>
#include <math.h>

// Hyena filter: k = MLP(z)·decay ; out = irfft(rfft(x,8192)*rfft(k,8192))[:4096] + x*bias
// FFT: rfft(8192 real) via complex FFT of N=4096 (even/odd packing),
// radix-8 Stockham (4 passes), 512 threads, in-place in LDS. (R9 radix-16
// regressed: 256-thread blocks halved occupancy; reverted to R8 base.)
// R10: (a) global twiddle tables T[512][8]=e^{-2pi i m r/4096} (+W0T[512] for
//      the combine), filled in mlp_kernel. All pass twiddles become 4 float4
//      L1-resident loads on the idle VMEM pipe instead of sincos+cmul chains
//      (inverse via conj -> cmuljv; pass<8>: row 64m, pass<64>: row 8m,
//      pass<512>+epilogue: row m).
//      (b) fwd pass<512> + spectral combine + inverse pass 1 fused in regs:
//      pass<512>'s write slots ARE the thread's own read slots (base=j), so
//      only the 4 upper bins (needed by partner p=512-t) go to LDS; combine
//      reads/writes the pair-exclusive partner slots; inverse pass 1 runs
//      from registers. LDS ops 112->96, barriers 17->13 per row.

#define PAD(i) ((i) + ((i) >> 4))
#define TWO_PI 6.2831853071795864769f
#define C8 0.70710678118654752440f

typedef __attribute__((ext_vector_type(2))) float cplx;

static __device__ __forceinline__ cplx mkc(float x, float y) { cplx c; c.x = x; c.y = y; return c; }
static __device__ __forceinline__ cplx cswap(cplx v)  { return __builtin_shufflevector(v, v, 1, 0); }
static __device__ __forceinline__ cplx cimul(cplx v)  { return __builtin_shufflevector(v, -v, 3, 0); }  // i*v
static __device__ __forceinline__ cplx cnimul(cplx v) { return __builtin_shufflevector(v, -v, 1, 2); }  // -i*v
static __device__ __forceinline__ cplx cconj(cplx v)  { return __builtin_shufflevector(v, -v, 0, 3); }
static __device__ __forceinline__ cplx splx(cplx v)   { return __builtin_shufflevector(v, v, 0, 0); }
static __device__ __forceinline__ cplx sply(cplx v)   { return __builtin_shufflevector(v, v, 1, 1); }

static __device__ __forceinline__ cplx cmulv(cplx a, cplx b) {
    return splx(b) * a + sply(b) * cimul(a);
}
static __device__ __forceinline__ cplx cmuljv(cplx a, cplx b) {   // conj(a)*b
    return splx(a) * b + sply(a) * cnimul(b);
}

// 8-point DFT, natural order in/out. FWD: sgn=-1. (verified R8 dataflow)
template <bool FWD>
__device__ __forceinline__ void dft8_pk(cplx v[8]) {
    const cplx w15 = FWD ? mkc(C8, -C8) : mkc(C8, C8);
    const cplx w37 = FWD ? mkc(-C8, -C8) : mkc(-C8, C8);
    cplx s0 = v[0] + v[4], s1 = v[0] - v[4];
    cplx s2 = v[2] + v[6], s3 = v[2] - v[6];
    cplx s4 = v[1] + v[5], s5 = v[1] - v[5];
    cplx s6 = v[3] + v[7], s7 = v[3] - v[7];
    cplx g0 = s0 + s2, g2 = s0 - s2;
    cplx g1 = FWD ? (s1 + cnimul(s3)) : (s1 + cimul(s3));
    cplx g3 = FWD ? (s1 + cimul(s3)) : (s1 + cnimul(s3));
    cplx g4 = s4 + s6, g6 = s4 - s6;
    cplx g5 = FWD ? (s5 + cnimul(s7)) : (s5 + cimul(s7));
    cplx g7 = FWD ? (s5 + cimul(s7)) : (s5 + cnimul(s7));
    v[0] = g0 + g4; v[4] = g0 - g4;
    cplx bt1 = cmulv(g5, w15);
    v[1] = g1 + bt1; v[5] = g1 - bt1;
    v[2] = FWD ? (g2 + cnimul(g6)) : (g2 + cimul(g6));
    v[6] = FWD ? (g2 + cimul(g6)) : (g2 + cnimul(g6));
    cplx bt3 = cmulv(g7, w37);
    v[3] = g3 + bt3; v[7] = g3 - bt3;
}

// inverse dft8 computing only v[0..3] (epilogue needs lower half only)
__device__ __forceinline__ void dft8_lo4_inv(cplx v[8]) {
    const cplx w15 = mkc(C8, C8), w37 = mkc(-C8, C8);
    cplx s0 = v[0] + v[4], s1 = v[0] - v[4];
    cplx s2 = v[2] + v[6], s3 = v[2] - v[6];
    cplx s4 = v[1] + v[5], s5 = v[1] - v[5];
    cplx s6 = v[3] + v[7], s7 = v[3] - v[7];
    cplx g0 = s0 + s2, g2 = s0 - s2;
    cplx g1 = s1 + cimul(s3), g3 = s1 + cnimul(s3);
    cplx g4 = s4 + s6, g6 = s4 - s6;
    cplx g5 = s5 + cimul(s7), g7 = s5 + cnimul(s7);
    v[0] = g0 + g4;
    v[1] = g1 + cmulv(g5, w15);
    v[2] = g2 + cimul(g6);
    v[3] = g3 + cmulv(g7, w37);
}

// Load w^1..w^7 for a table row (64 B, 16B-aligned) as 4x float4.
__device__ __forceinline__ void load_tw(const cplx* __restrict__ T, int row, cplx w[8]) {
    const float4* tp = (const float4*)(T + ((size_t)row << 3));
    float4 q0 = tp[0], q1 = tp[1], q2 = tp[2], q3 = tp[3];
    w[1] = mkc(q0.z, q0.w);
    w[2] = mkc(q1.x, q1.y); w[3] = mkc(q1.z, q1.w);
    w[4] = mkc(q2.x, q2.y); w[5] = mkc(q2.z, q2.w);
    w[6] = mkc(q3.x, q3.y); w[7] = mkc(q3.z, q3.w);
}

// One Stockham radix-8 pass over N=4096 in LDS, in place. 512 threads, j = tid.
// Twiddles from global table (FWD direct, inverse = conj).
template <int NS, bool FWD>
__device__ __forceinline__ void fft_pass_ip_tw(cplx* __restrict__ buf, int j,
                                               const cplx* __restrict__ T) {
    cplx* rp = buf + (j + (j >> 4));
    cplx v[8];
#pragma unroll
    for (int r = 0; r < 8; r++) v[r] = rp[544 * r];
    {
        int row = (j & (NS - 1)) * (512 / NS);
        cplx w[8];
        load_tw(T, row, w);
#pragma unroll
        for (int r = 1; r < 8; r++) v[r] = FWD ? cmulv(v[r], w[r]) : cmuljv(w[r], v[r]);
    }
    dft8_pk<FWD>(v);
    __syncthreads();                       // everyone done reading
    int base = ((j & ~(NS - 1)) << 3) + (j & (NS - 1));
    cplx* wp = buf + (base + (base >> 4));
#pragma unroll
    for (int r = 0; r < 8; r++) {
        const int off = (NS == 8) ? (8 * r + (r >> 1))
                      : (NS == 64) ? (68 * r)
                      : (544 * r);
        wp[off] = v[r];
    }
    __syncthreads();
}

// Forward FFT pass 1 (NS=1) from registers; upper half zero, hand-folded.
__device__ __forceinline__ void fft_pass1_fwd_regs(cplx* __restrict__ buf, int j,
                                                   const cplx xv[4]) {
    const cplx w15 = mkc(C8, -C8), w37 = mkc(-C8, -C8);
    cplx a0 = xv[0] + xv[2], a2 = xv[0] - xv[2];
    cplx a1 = xv[0] + cnimul(xv[2]), a3 = xv[0] + cimul(xv[2]);
    cplx b0 = xv[1] + xv[3], b2 = xv[1] - xv[3];
    cplx b1 = xv[1] + cnimul(xv[3]), b3 = xv[1] + cimul(xv[3]);
    cplx v[8];
    v[0] = a0 + b0; v[4] = a0 - b0;
    cplx bt1 = cmulv(b1, w15);
    v[1] = a1 + bt1; v[5] = a1 - bt1;
    v[2] = a2 + cnimul(b2); v[6] = a2 + cimul(b2);
    cplx bt3 = cmulv(b3, w37);
    v[3] = a3 + bt3; v[7] = a3 - bt3;
    int b8 = 8 * j;
    cplx* wp = buf + (b8 + (b8 >> 4));
#pragma unroll
    for (int r = 0; r < 8; r++) wp[r] = v[r];
    __syncthreads();
}

// combine twiddle constants W16^i = e^{-2pi i * 512 i / 8192}
#define W16_TABLE                                                             \
    const cplx W16C1 = mkc(0.92387953251128675613f, -0.38268343236508977173f);\
    const cplx W16C2 = mkc(0.70710678118654752440f, -0.70710678118654752440f);\
    const cplx W16C3 = mkc(0.38268343236508977173f, -0.92387953251128675613f);

// ---------------- Kernel 1: positional MLP -> h3T (64 x 4096) ----------------
// Also fills the twiddle tables T[512][8] and W0T[512].
__global__ __launch_bounds__(256) void mlp_kernel(
    const float* __restrict__ zin, const float* __restrict__ W1,
    const float* __restrict__ b1, const float* __restrict__ freq,
    const float* __restrict__ W2, const float* __restrict__ b2,
    const float* __restrict__ W3, const float* __restrict__ b3,
    float* __restrict__ h3T, cplx* __restrict__ T, cplx* __restrict__ W0T) {
    int tid = threadIdx.x;
    int g = blockIdx.x * 256 + tid;        // 0..16383
    if (g < 4096) {                        // T[m][r], m=g>>3, r=g&7
        int m = g >> 3, r = g & 7;
        int e = (m * r) & 4095;
        float s, c;
        __sincosf(-TWO_PI * (float)e * (1.0f / 4096.0f), &s, &c);
        T[g] = mkc(c, s);
    }
    if (g < 512) {
        float s, c;
        __sincosf(-TWO_PI * (float)g * (1.0f / 8192.0f), &s, &c);
        W0T[g] = mkc(c, s);
    }

    __shared__ float hs1[64][64];
    __shared__ float hs2[64][64];
    int l = tid & 63, w = tid >> 6;
    int lg = blockIdx.x * 64 + l;          // grid = 64 blocks covers 4096

    float zf[5];
#pragma unroll
    for (int e = 0; e < 5; e++) zf[e] = zin[lg * 5 + e];

    // layer 1
#pragma unroll
    for (int i = 0; i < 16; i++) {
        int o = w * 16 + i;
        float a = b1[o];
#pragma unroll
        for (int e = 0; e < 5; e++) a += W1[o * 5 + e] * zf[e];
        hs1[o][l] = __sinf(freq[o] * a);
    }
    __syncthreads();

    // layer 2
    float acc[16];
#pragma unroll
    for (int i = 0; i < 16; i++) acc[i] = b2[w * 16 + i];
#pragma unroll 8
    for (int o = 0; o < 64; o++) {
        float hv = hs1[o][l];
#pragma unroll
        for (int i = 0; i < 16; i++) acc[i] += W2[(w * 16 + i) * 64 + o] * hv;
    }
#pragma unroll
    for (int i = 0; i < 16; i++)
        hs2[w * 16 + i][l] = __sinf(freq[w * 16 + i] * acc[i]);
    __syncthreads();

    // layer 3
#pragma unroll
    for (int i = 0; i < 16; i++) acc[i] = b3[w * 16 + i];
#pragma unroll 8
    for (int o = 0; o < 64; o++) {
        float hv = hs2[o][l];
#pragma unroll
        for (int i = 0; i < 16; i++) acc[i] += W3[(w * 16 + i) * 64 + o] * hv;
    }
#pragma unroll
    for (int i = 0; i < 16; i++)
        h3T[(size_t)(w * 16 + i) * 4096 + lg] = __sinf(freq[w * 16 + i] * acc[i]);
}

// -------- Kernel 2: k[d,l] = <h3[:,l], W4[d,:]> * exp(-t[l]*|delta[d]|) --------
__global__ __launch_bounds__(256) void kgemm_kernel(
    const float* __restrict__ h3T, const float* __restrict__ W4,
    const float* __restrict__ tvec, const float* __restrict__ deltas,
    float* __restrict__ kout) {
    int lt = blockIdx.x & 3;       // l tile (4 x 1024)
    int dt = blockIdx.x >> 2;      // d tile (64 x 16)
    int l0 = lt * 1024 + threadIdx.x * 4;
    float4 acc[16];
#pragma unroll
    for (int i = 0; i < 16; i++) acc[i] = make_float4(0.f, 0.f, 0.f, 0.f);
#pragma unroll 8
    for (int o = 0; o < 64; o++) {
        float4 h = *(const float4*)(h3T + (size_t)o * 4096 + l0);
#pragma unroll
        for (int i = 0; i < 16; i++) {
            float wv = W4[(size_t)(dt * 16 + i) * 64 + o];
            acc[i].x += wv * h.x; acc[i].y += wv * h.y;
            acc[i].z += wv * h.z; acc[i].w += wv * h.w;
        }
    }
    float4 tl = *(const float4*)(tvec + l0);
#pragma unroll
    for (int i = 0; i < 16; i++) {
        int d = dt * 16 + i;
        float da = fabsf(deltas[d]);
        float4 o;
        o.x = acc[i].x * __expf(-tl.x * da);
        o.y = acc[i].y * __expf(-tl.y * da);
        o.z = acc[i].z * __expf(-tl.z * da);
        o.w = acc[i].w * __expf(-tl.w * da);
        *(float4*)(kout + (size_t)d * 4096 + l0) = o;
    }
}

// ------- Kernel 3: per-channel rfft(k,8192) -> Kf[d][0..4096] -------
// Kf stored with 1/4096 inverse-FFT scale folded in. Row stride 4104 complexes.
__global__ __launch_bounds__(512) void filter_fft_kernel(
    const float* __restrict__ kin, cplx* __restrict__ Kf,
    const cplx* __restrict__ T, const cplx* __restrict__ W0T) {
    __shared__ cplx buf[4352];
    int d = blockIdx.x, t = threadIdx.x;

    const cplx* k2 = (const cplx*)(kin + (size_t)d * 4096);
    cplx xv[4];
#pragma unroll
    for (int r = 0; r < 4; r++) xv[r] = k2[t + (r << 9)];
    fft_pass1_fwd_regs(buf, t, xv);
    fft_pass_ip_tw<8, true>(buf, t, T);
    fft_pass_ip_tw<64, true>(buf, t, T);

    // fused fwd pass<512>: bins Z[t+512r] stay in regs; write upper 4 for partner
    cplx* rp = buf + (t + (t >> 4));
    cplx zv[8];
    {
#pragma unroll
        for (int r = 0; r < 8; r++) zv[r] = rp[544 * r];
        cplx w[8];
        load_tw(T, t, w);
#pragma unroll
        for (int r = 1; r < 8; r++) zv[r] = cmulv(zv[r], w[r]);
        dft8_pk<true>(zv);
    }
    // write slots == own read slots (base=t): no pre-write barrier needed
#pragma unroll
    for (int r = 4; r < 8; r++) rp[544 * r] = zv[r];
    __syncthreads();

    const float scale = 1.0f / 4096.0f;
    cplx w0 = W0T[t];
    W16_TABLE
    cplx wk[4];
    wk[0] = w0;
    wk[1] = cmulv(w0, W16C1);
    wk[2] = cmulv(w0, W16C2);
    wk[3] = cmulv(w0, W16C3);
    cplx* KfRow = Kf + (size_t)d * 4104;
    if (t == 0) {
        cplx z0 = zv[0];
        KfRow[0]    = mkc((z0.x + z0.y) * scale, 0.f);
        KfRow[4096] = mkc((z0.x - z0.y) * scale, 0.f);
        cplx zm = zv[4];                   // Z[2048]
        KfRow[2048] = mkc(zm.x * scale, -zm.y * scale);
#pragma unroll
        for (int i = 1; i < 4; i++) {
            cplx Zk = zv[i];
            cplx Zq = zv[8 - i];           // Z[4096-512i], own regs
            cplx Fe = 0.5f * (Zk + cconj(Zq));
            cplx Fo = 0.5f * (cnimul(Zk) + cswap(Zq));
            cplx WFo = cmulv(wk[i], Fo);
            KfRow[512 * i]        = scale * (Fe + WFo);
            KfRow[4096 - 512 * i] = scale * cconj(Fe - WFo);
        }
    } else {
        int p = 512 - t;
        cplx* pb = buf + (p + (p >> 4));
        cplx* kfp = KfRow + t;
        cplx* kfq = KfRow + (4096 - t);
#pragma unroll
        for (int i = 0; i < 4; i++) {
            cplx Zk = zv[i];
            cplx Zq = pb[544 * (7 - i)];   // Z[4096-t-512i] from partner
            cplx Fe = 0.5f * (Zk + cconj(Zq));
            cplx Fo = 0.5f * (cnimul(Zk) + cswap(Zq));
            cplx WFo = cmulv(wk[i], Fo);
            kfp[512 * i]  = scale * (Fe + WFo);
            kfq[-512 * i] = scale * cconj(Fe - WFo);
        }
    }
}

// ------- Kernel 4: per (b,d) row: FFT -> spectral multiply -> IFFT -> +x*bias -------
__global__ __launch_bounds__(512) void conv_kernel(
    const float* __restrict__ x, const cplx* __restrict__ Kf,
    const cplx* __restrict__ T, const cplx* __restrict__ W0T,
    const float* __restrict__ bias, float* __restrict__ out) {
    __shared__ cplx buf[4352];
    int rid = blockIdx.x;          // rid = b*1024 + d
    int d = rid & 1023;
    int t = threadIdx.x;

    const cplx* x2 = (const cplx*)(x + (size_t)rid * 4096);
    cplx xv[4];
#pragma unroll
    for (int r = 0; r < 4; r++) xv[r] = x2[t + (r << 9)];
    fft_pass1_fwd_regs(buf, t, xv);
    fft_pass_ip_tw<8, true>(buf, t, T);
    fft_pass_ip_tw<64, true>(buf, t, T);

    // fused fwd pass<512>: Z[t+512r] in regs; write upper 4 for partner
    cplx* rp = buf + (t + (t >> 4));
    cplx zv[8];
    {
#pragma unroll
        for (int r = 0; r < 8; r++) zv[r] = rp[544 * r];
        cplx w[8];
        load_tw(T, t, w);
#pragma unroll
        for (int r = 1; r < 8; r++) zv[r] = cmulv(zv[r], w[r]);
        dft8_pk<true>(zv);
    }
#pragma unroll
    for (int r = 4; r < 8; r++) rp[544 * r] = zv[r];
    __syncthreads();

    // spectral combine; own lower Z' -> regs (yl), partner upper Z' -> partner slots
    cplx yl[4];
    {
        cplx w0 = W0T[t];
        W16_TABLE
        cplx wk[4];
        wk[0] = w0;
        wk[1] = cmulv(w0, W16C1);
        wk[2] = cmulv(w0, W16C2);
        wk[3] = cmulv(w0, W16C3);
        const cplx* KfRow = Kf + (size_t)d * 4104;
        if (t == 0) {
            cplx z0 = zv[0];
            float U0 = z0.x + z0.y;
            float UN = z0.x - z0.y;
            float Y0 = U0 * KfRow[0].x;
            float YN = UN * KfRow[4096].x;
            yl[0] = mkc(0.5f * (Y0 + YN), 0.5f * (Y0 - YN));
            cplx zm = zv[4];                              // Z[2048]
            cplx Km = KfRow[2048];
            cplx Ym = cmuljv(zm, Km);                     // conj(Z)*K
            rp[544 * 4] = mkc(Ym.x, -Ym.y);               // Z'[2048]
#pragma unroll
            for (int i = 1; i < 4; i++) {
                cplx Zk = zv[i];
                cplx Zq = zv[8 - i];                      // own regs
                cplx K1 = KfRow[512 * i], K2 = KfRow[4096 - 512 * i];
                cplx Fe = 0.5f * (Zk + cconj(Zq));
                cplx Fo = 0.5f * (cnimul(Zk) + cswap(Zq));
                cplx WFo = cmulv(wk[i], Fo);
                cplx U1 = Fe + WFo;
                cplx U2 = cconj(Fe - WFo);
                cplx Y1 = cmulv(U1, K1);
                cplx Y2 = cmulv(U2, K2);
                cplx FeY = 0.5f * (Y1 + cconj(Y2));
                cplx Tv  = 0.5f * (Y1 - cconj(Y2));
                cplx FoY = cmuljv(wk[i], Tv);
                yl[i] = FeY + cimul(FoY);                 // Z'[512i]
                rp[544 * (8 - i)] = cconj(FeY - cimul(FoY)); // Z'[4096-512i]
            }
        } else {
            int p = 512 - t;
            cplx* pb = buf + (p + (p >> 4));
            const cplx* kfp = KfRow + t;
            const cplx* kfq = KfRow + (4096 - t);
#pragma unroll
            for (int i = 0; i < 4; i++) {
                cplx Zk = zv[i];
                cplx Zq = pb[544 * (7 - i)];              // partner's Z[4096-k]
                cplx K1 = kfp[512 * i], K2 = kfq[-512 * i];
                cplx Fe = 0.5f * (Zk + cconj(Zq));
                cplx Fo = 0.5f * (cnimul(Zk) + cswap(Zq));
                cplx WFo = cmulv(wk[i], Fo);
                cplx U1 = Fe + WFo;
                cplx U2 = cconj(Fe - WFo);
                cplx Y1 = cmulv(U1, K1);
                cplx Y2 = cmulv(U2, K2);
                cplx FeY = 0.5f * (Y1 + cconj(Y2));
                cplx Tv  = 0.5f * (Y1 - cconj(Y2));
                cplx FoY = cmuljv(wk[i], Tv);
                yl[i] = FeY + cimul(FoY);                 // Z'[t+512i]
                pb[544 * (7 - i)] = cconj(FeY - cimul(FoY)); // Z'[4096-k]
            }
        }
    }
    __syncthreads();                       // partner's Z' writes visible

    // read back own upper Z' (written by partner), then inverse pass 1 from regs
    cplx v[8];
#pragma unroll
    for (int i = 0; i < 4; i++) v[i] = yl[i];
#pragma unroll
    for (int s = 0; s < 4; s++) v[4 + s] = rp[544 * (4 + s)];
    __syncthreads();                       // all reads done before pass-1 writes
    dft8_pk<false>(v);
    {
        int b8 = 8 * t;
        cplx* wp = buf + (b8 + (b8 >> 4));
#pragma unroll
        for (int r = 0; r < 8; r++) wp[r] = v[r];
    }
    __syncthreads();
    fft_pass_ip_tw<8, false>(buf, t, T);
    fft_pass_ip_tw<64, false>(buf, t, T);

    // inverse last pass (NS=512) fused with the global store (only m<2048 needed)
    {
        cplx u[8];
#pragma unroll
        for (int r = 0; r < 8; r++) u[r] = rp[544 * r];
        cplx w[8];
        load_tw(T, t, w);
#pragma unroll
        for (int r = 1; r < 8; r++) u[r] = cmuljv(w[r], u[r]);   // conj twiddle
        dft8_lo4_inv(u);
        float bd = bias[d];
        cplx* o2 = (cplx*)(out + (size_t)rid * 4096);
#pragma unroll
        for (int r = 0; r < 4; r++) {                    // m = t + r*512 < 2048
            o2[t + (r << 9)] = u[r] + bd * xv[r];
        }
    }
}

extern "C" void kernel_launch(void* const* d_in, const int* in_sizes, int n_in,
                              void* d_out, int out_size, void* d_ws, size_t ws_size,
                              hipStream_t stream) {
    const float* x      = (const float*)d_in[0];
    // d_in[1] = L (int scalar) — compile-time constant 4096 here
    const float* zin    = (const float*)d_in[2];
    const float* tvec   = (const float*)d_in[3];
    const float* deltas = (const float*)d_in[4];
    const float* W1     = (const float*)d_in[5];
    const float* b1     = (const float*)d_in[6];
    const float* freq   = (const float*)d_in[7];
    const float* W2     = (const float*)d_in[8];
    const float* b2     = (const float*)d_in[9];
    const float* W3     = (const float*)d_in[10];
    const float* b3     = (const float*)d_in[11];
    const float* W4     = (const float*)d_in[12];
    const float* bias   = (const float*)d_in[13];
    float* out = (float*)d_out;

    // ws layout: h3T (1 MB) | Kf (1024*4104 cplx = 33.6 MB) | T (32 KB) | W0T (4 KB)
    float* h3T = (float*)d_ws;
    cplx*  Kf  = (cplx*)((char*)d_ws + (size_t)1048576);
    cplx*  Tt  = (cplx*)((char*)d_ws + (size_t)1048576 + (size_t)33619968);
    cplx*  W0T = (cplx*)((char*)d_ws + (size_t)1048576 + (size_t)33619968 + 32768);
    // k (1024x4096 f32 = 16 MB) staged in the tail of d_out (64 MB); conv
    // overwrites it afterwards (stream-ordered: kgemm -> filter_fft -> conv).
    float* kbuf = out + (size_t)3072 * 4096;

    mlp_kernel<<<64, 256, 0, stream>>>(zin, W1, b1, freq, W2, b2, W3, b3, h3T, Tt, W0T);
    kgemm_kernel<<<256, 256, 0, stream>>>(h3T, W4, tvec, deltas, kbuf);
    filter_fft_kernel<<<1024, 512, 0, stream>>>(kbuf, Kf, Tt, W0T);
    conv_kernel<<<4096, 512, 0, stream>>>(x, Kf, Tt, W0T, bias, out);
}

// Round 8
// 249.761 us; speedup vs baseline: 1.1115x; 1.1115x over previous
//
#include <hip/hip_runtime.h>
#include <math.h>

// Hyena filter: k = MLP(z)·decay ; out = irfft(rfft(x,8192)*rfft(k,8192))[:4096] + x*bias
// FFT: rfft(8192 real) via complex FFT of N=4096 (even/odd packing),
// radix-8 Stockham (4 passes), 512 threads, in-place in LDS.
// R8:  ext_vector(2) complex helpers, PAD identities, sincos twiddle chains.
// R10 post-mortem: global twiddle TABLES regressed 72.6->123us (VALUBusy
//      70->33%: table loads latency-stall every pass; sincos VALU chains
//      overlap instead). Tables REVERTED here.
// R11: keep R10's register fusion only: fwd pass<512>'s write slots ARE the
//      thread's own read slots (base=t for NS=512), so bins Z[t+512r] stay in
//      regs and only the 4 upper bins go to LDS for partner p=512-t; combine
//      reads/writes pair-exclusive partner slots; inverse pass 1 runs from
//      registers. LDS ops 128->108, barriers 14->13 per row.

#define PAD(i) ((i) + ((i) >> 4))
#define TWO_PI 6.2831853071795864769f
#define C8 0.70710678118654752440f

typedef __attribute__((ext_vector_type(2))) float cplx;

static __device__ __forceinline__ cplx mkc(float x, float y) { cplx c; c.x = x; c.y = y; return c; }
static __device__ __forceinline__ cplx cswap(cplx v)  { return __builtin_shufflevector(v, v, 1, 0); }
static __device__ __forceinline__ cplx cimul(cplx v)  { return __builtin_shufflevector(v, -v, 3, 0); }  // i*v
static __device__ __forceinline__ cplx cnimul(cplx v) { return __builtin_shufflevector(v, -v, 1, 2); }  // -i*v
static __device__ __forceinline__ cplx cconj(cplx v)  { return __builtin_shufflevector(v, -v, 0, 3); }
static __device__ __forceinline__ cplx splx(cplx v)   { return __builtin_shufflevector(v, v, 0, 0); }
static __device__ __forceinline__ cplx sply(cplx v)   { return __builtin_shufflevector(v, v, 1, 1); }

static __device__ __forceinline__ cplx cmulv(cplx a, cplx b) {
    return splx(b) * a + sply(b) * cimul(a);
}
static __device__ __forceinline__ cplx cmuljv(cplx a, cplx b) {   // conj(a)*b
    return splx(a) * b + sply(a) * cnimul(b);
}

// 8-point DFT, natural order in/out. FWD: sgn=-1. (verified R8 dataflow)
template <bool FWD>
__device__ __forceinline__ void dft8_pk(cplx v[8]) {
    const cplx w15 = FWD ? mkc(C8, -C8) : mkc(C8, C8);
    const cplx w37 = FWD ? mkc(-C8, -C8) : mkc(-C8, C8);
    cplx s0 = v[0] + v[4], s1 = v[0] - v[4];
    cplx s2 = v[2] + v[6], s3 = v[2] - v[6];
    cplx s4 = v[1] + v[5], s5 = v[1] - v[5];
    cplx s6 = v[3] + v[7], s7 = v[3] - v[7];
    cplx g0 = s0 + s2, g2 = s0 - s2;
    cplx g1 = FWD ? (s1 + cnimul(s3)) : (s1 + cimul(s3));
    cplx g3 = FWD ? (s1 + cimul(s3)) : (s1 + cnimul(s3));
    cplx g4 = s4 + s6, g6 = s4 - s6;
    cplx g5 = FWD ? (s5 + cnimul(s7)) : (s5 + cimul(s7));
    cplx g7 = FWD ? (s5 + cimul(s7)) : (s5 + cnimul(s7));
    v[0] = g0 + g4; v[4] = g0 - g4;
    cplx bt1 = cmulv(g5, w15);
    v[1] = g1 + bt1; v[5] = g1 - bt1;
    v[2] = FWD ? (g2 + cnimul(g6)) : (g2 + cimul(g6));
    v[6] = FWD ? (g2 + cimul(g6)) : (g2 + cnimul(g6));
    cplx bt3 = cmulv(g7, w37);
    v[3] = g3 + bt3; v[7] = g3 - bt3;
}

// inverse dft8 computing only v[0..3] (epilogue needs lower half only)
__device__ __forceinline__ void dft8_lo4_inv(cplx v[8]) {
    const cplx w15 = mkc(C8, C8), w37 = mkc(-C8, C8);
    cplx s0 = v[0] + v[4], s1 = v[0] - v[4];
    cplx s2 = v[2] + v[6], s3 = v[2] - v[6];
    cplx s4 = v[1] + v[5], s5 = v[1] - v[5];
    cplx s6 = v[3] + v[7], s7 = v[3] - v[7];
    cplx g0 = s0 + s2, g2 = s0 - s2;
    cplx g1 = s1 + cimul(s3), g3 = s1 + cnimul(s3);
    cplx g4 = s4 + s6, g6 = s4 - s6;
    cplx g5 = s5 + cimul(s7), g7 = s5 + cnimul(s7);
    v[0] = g0 + g4;
    v[1] = g1 + cmulv(g5, w15);
    v[2] = g2 + cimul(g6);
    v[3] = g3 + cmulv(g7, w37);
}

// Build w^1..w^7 from one sincos via shallow (depth<=3) cmul chains.
__device__ __forceinline__ void twiddle_powers(float ang, cplx w[8]) {
    float s, c;
    __sincosf(ang, &s, &c);
    w[1] = mkc(c, s);
    w[2] = cmulv(w[1], w[1]);
    w[3] = cmulv(w[2], w[1]);
    w[4] = cmulv(w[2], w[2]);
    w[5] = cmulv(w[4], w[1]);
    w[6] = cmulv(w[3], w[3]);
    w[7] = cmulv(w[4], w[3]);
}

// One Stockham radix-8 pass over N=4096 in LDS, in place. 512 threads, j = tid.
template <int NS, bool FWD>
__device__ __forceinline__ void fft_pass_ip(cplx* __restrict__ buf, int j) {
    cplx* rp = buf + (j + (j >> 4));
    cplx v[8];
#pragma unroll
    for (int r = 0; r < 8; r++) v[r] = rp[544 * r];
    if (NS > 1) {
        int jm = j & (NS - 1);
        float ang = (FWD ? -1.0f : 1.0f) * (TWO_PI / (float)(NS * 8)) * (float)jm;
        cplx w[8];
        twiddle_powers(ang, w);
#pragma unroll
        for (int r = 1; r < 8; r++) v[r] = cmulv(v[r], w[r]);
    }
    dft8_pk<FWD>(v);
    __syncthreads();                       // everyone done reading
    int base = ((j & ~(NS - 1)) << 3) + (j & (NS - 1));
    cplx* wp = buf + (base + (base >> 4));
#pragma unroll
    for (int r = 0; r < 8; r++) {
        const int off = (NS == 1) ? r
                      : (NS == 8) ? (8 * r + (r >> 1))
                      : (NS == 64) ? (68 * r)
                      : (544 * r);
        wp[off] = v[r];
    }
    __syncthreads();
}

// Forward FFT pass 1 (NS=1) from registers; upper half zero, hand-folded.
__device__ __forceinline__ void fft_pass1_fwd_regs(cplx* __restrict__ buf, int j,
                                                   const cplx xv[4]) {
    const cplx w15 = mkc(C8, -C8), w37 = mkc(-C8, -C8);
    cplx a0 = xv[0] + xv[2], a2 = xv[0] - xv[2];
    cplx a1 = xv[0] + cnimul(xv[2]), a3 = xv[0] + cimul(xv[2]);
    cplx b0 = xv[1] + xv[3], b2 = xv[1] - xv[3];
    cplx b1 = xv[1] + cnimul(xv[3]), b3 = xv[1] + cimul(xv[3]);
    cplx v[8];
    v[0] = a0 + b0; v[4] = a0 - b0;
    cplx bt1 = cmulv(b1, w15);
    v[1] = a1 + bt1; v[5] = a1 - bt1;
    v[2] = a2 + cnimul(b2); v[6] = a2 + cimul(b2);
    cplx bt3 = cmulv(b3, w37);
    v[3] = a3 + bt3; v[7] = a3 - bt3;
    int b8 = 8 * j;
    cplx* wp = buf + (b8 + (b8 >> 4));
#pragma unroll
    for (int r = 0; r < 8; r++) wp[r] = v[r];
    __syncthreads();
}

// combine twiddle constants W16^i = e^{-2pi i * 512 i / 8192}
#define W16_TABLE                                                             \
    const cplx W16C1 = mkc(0.92387953251128675613f, -0.38268343236508977173f);\
    const cplx W16C2 = mkc(0.70710678118654752440f, -0.70710678118654752440f);\
    const cplx W16C3 = mkc(0.38268343236508977173f, -0.92387953251128675613f);

// ---------------- Kernel 1: positional MLP -> h3T (64 x 4096) ----------------
__global__ __launch_bounds__(256) void mlp_kernel(
    const float* __restrict__ zin, const float* __restrict__ W1,
    const float* __restrict__ b1, const float* __restrict__ freq,
    const float* __restrict__ W2, const float* __restrict__ b2,
    const float* __restrict__ W3, const float* __restrict__ b3,
    float* __restrict__ h3T) {
    __shared__ float hs1[64][64];
    __shared__ float hs2[64][64];
    int tid = threadIdx.x;
    int l = tid & 63, w = tid >> 6;
    int lg = blockIdx.x * 64 + l;          // grid = 64 blocks covers 4096

    float zf[5];
#pragma unroll
    for (int e = 0; e < 5; e++) zf[e] = zin[lg * 5 + e];

    // layer 1
#pragma unroll
    for (int i = 0; i < 16; i++) {
        int o = w * 16 + i;
        float a = b1[o];
#pragma unroll
        for (int e = 0; e < 5; e++) a += W1[o * 5 + e] * zf[e];
        hs1[o][l] = __sinf(freq[o] * a);
    }
    __syncthreads();

    // layer 2
    float acc[16];
#pragma unroll
    for (int i = 0; i < 16; i++) acc[i] = b2[w * 16 + i];
#pragma unroll 8
    for (int o = 0; o < 64; o++) {
        float hv = hs1[o][l];
#pragma unroll
        for (int i = 0; i < 16; i++) acc[i] += W2[(w * 16 + i) * 64 + o] * hv;
    }
#pragma unroll
    for (int i = 0; i < 16; i++)
        hs2[w * 16 + i][l] = __sinf(freq[w * 16 + i] * acc[i]);
    __syncthreads();

    // layer 3
#pragma unroll
    for (int i = 0; i < 16; i++) acc[i] = b3[w * 16 + i];
#pragma unroll 8
    for (int o = 0; o < 64; o++) {
        float hv = hs2[o][l];
#pragma unroll
        for (int i = 0; i < 16; i++) acc[i] += W3[(w * 16 + i) * 64 + o] * hv;
    }
#pragma unroll
    for (int i = 0; i < 16; i++)
        h3T[(size_t)(w * 16 + i) * 4096 + lg] = __sinf(freq[w * 16 + i] * acc[i]);
}

// -------- Kernel 2: k[d,l] = <h3[:,l], W4[d,:]> * exp(-t[l]*|delta[d]|) --------
__global__ __launch_bounds__(256) void kgemm_kernel(
    const float* __restrict__ h3T, const float* __restrict__ W4,
    const float* __restrict__ tvec, const float* __restrict__ deltas,
    float* __restrict__ kout) {
    int lt = blockIdx.x & 3;       // l tile (4 x 1024)
    int dt = blockIdx.x >> 2;      // d tile (64 x 16)
    int l0 = lt * 1024 + threadIdx.x * 4;
    float4 acc[16];
#pragma unroll
    for (int i = 0; i < 16; i++) acc[i] = make_float4(0.f, 0.f, 0.f, 0.f);
#pragma unroll 8
    for (int o = 0; o < 64; o++) {
        float4 h = *(const float4*)(h3T + (size_t)o * 4096 + l0);
#pragma unroll
        for (int i = 0; i < 16; i++) {
            float wv = W4[(size_t)(dt * 16 + i) * 64 + o];
            acc[i].x += wv * h.x; acc[i].y += wv * h.y;
            acc[i].z += wv * h.z; acc[i].w += wv * h.w;
        }
    }
    float4 tl = *(const float4*)(tvec + l0);
#pragma unroll
    for (int i = 0; i < 16; i++) {
        int d = dt * 16 + i;
        float da = fabsf(deltas[d]);
        float4 o;
        o.x = acc[i].x * __expf(-tl.x * da);
        o.y = acc[i].y * __expf(-tl.y * da);
        o.z = acc[i].z * __expf(-tl.z * da);
        o.w = acc[i].w * __expf(-tl.w * da);
        *(float4*)(kout + (size_t)d * 4096 + l0) = o;
    }
}

// ------- Kernel 3: per-channel rfft(k,8192) -> Kf[d][0..4096] -------
// Kf stored with 1/4096 inverse-FFT scale folded in. Row stride 4104 complexes.
__global__ __launch_bounds__(512) void filter_fft_kernel(
    const float* __restrict__ kin, cplx* __restrict__ Kf) {
    __shared__ cplx buf[4352];
    int d = blockIdx.x, t = threadIdx.x;

    const cplx* k2 = (const cplx*)(kin + (size_t)d * 4096);
    cplx xv[4];
#pragma unroll
    for (int r = 0; r < 4; r++) xv[r] = k2[t + (r << 9)];
    fft_pass1_fwd_regs(buf, t, xv);
    fft_pass_ip<8, true>(buf, t);
    fft_pass_ip<64, true>(buf, t);

    // fused fwd pass<512>: bins Z[t+512r] stay in regs; write upper 4 for partner
    cplx* rp = buf + (t + (t >> 4));
    cplx zv[8];
    {
#pragma unroll
        for (int r = 0; r < 8; r++) zv[r] = rp[544 * r];
        cplx w[8];
        twiddle_powers(-TWO_PI * (float)t * (1.0f / 4096.0f), w);
#pragma unroll
        for (int r = 1; r < 8; r++) zv[r] = cmulv(zv[r], w[r]);
        dft8_pk<true>(zv);
    }
    // write slots == own read slots (base=t for NS=512): no pre-write barrier
#pragma unroll
    for (int r = 4; r < 8; r++) rp[544 * r] = zv[r];
    __syncthreads();

    const float scale = 1.0f / 4096.0f;
    float sb, cb;
    __sincosf(-TWO_PI * (float)t * (1.0f / 8192.0f), &sb, &cb);
    cplx w0 = mkc(cb, sb);
    W16_TABLE
    cplx wk[4];
    wk[0] = w0;
    wk[1] = cmulv(w0, W16C1);
    wk[2] = cmulv(w0, W16C2);
    wk[3] = cmulv(w0, W16C3);
    cplx* KfRow = Kf + (size_t)d * 4104;
    if (t == 0) {
        cplx z0 = zv[0];
        KfRow[0]    = mkc((z0.x + z0.y) * scale, 0.f);
        KfRow[4096] = mkc((z0.x - z0.y) * scale, 0.f);
        cplx zm = zv[4];                   // Z[2048]
        KfRow[2048] = mkc(zm.x * scale, -zm.y * scale);
#pragma unroll
        for (int i = 1; i < 4; i++) {
            cplx Zk = zv[i];
            cplx Zq = zv[8 - i];           // Z[4096-512i], own regs
            cplx Fe = 0.5f * (Zk + cconj(Zq));
            cplx Fo = 0.5f * (cnimul(Zk) + cswap(Zq));
            cplx WFo = cmulv(wk[i], Fo);
            KfRow[512 * i]        = scale * (Fe + WFo);
            KfRow[4096 - 512 * i] = scale * cconj(Fe - WFo);
        }
    } else {
        int p = 512 - t;
        cplx* pb = buf + (p + (p >> 4));
        cplx* kfp = KfRow + t;
        cplx* kfq = KfRow + (4096 - t);
#pragma unroll
        for (int i = 0; i < 4; i++) {
            cplx Zk = zv[i];
            cplx Zq = pb[544 * (7 - i)];   // Z[4096-t-512i] from partner
            cplx Fe = 0.5f * (Zk + cconj(Zq));
            cplx Fo = 0.5f * (cnimul(Zk) + cswap(Zq));
            cplx WFo = cmulv(wk[i], Fo);
            kfp[512 * i]  = scale * (Fe + WFo);
            kfq[-512 * i] = scale * cconj(Fe - WFo);
        }
    }
}

// ------- Kernel 4: per (b,d) row: FFT -> spectral multiply -> IFFT -> +x*bias -------
__global__ __launch_bounds__(512) void conv_kernel(
    const float* __restrict__ x, const cplx* __restrict__ Kf,
    const float* __restrict__ bias, float* __restrict__ out) {
    __shared__ cplx buf[4352];
    int rid = blockIdx.x;          // rid = b*1024 + d
    int d = rid & 1023;
    int t = threadIdx.x;

    const cplx* x2 = (const cplx*)(x + (size_t)rid * 4096);
    cplx xv[4];
#pragma unroll
    for (int r = 0; r < 4; r++) xv[r] = x2[t + (r << 9)];
    fft_pass1_fwd_regs(buf, t, xv);
    fft_pass_ip<8, true>(buf, t);
    fft_pass_ip<64, true>(buf, t);

    // fused fwd pass<512>: Z[t+512r] in regs; write upper 4 for partner
    cplx* rp = buf + (t + (t >> 4));
    cplx zv[8];
    {
#pragma unroll
        for (int r = 0; r < 8; r++) zv[r] = rp[544 * r];
        cplx w[8];
        twiddle_powers(-TWO_PI * (float)t * (1.0f / 4096.0f), w);
#pragma unroll
        for (int r = 1; r < 8; r++) zv[r] = cmulv(zv[r], w[r]);
        dft8_pk<true>(zv);
    }
#pragma unroll
    for (int r = 4; r < 8; r++) rp[544 * r] = zv[r];
    __syncthreads();

    // spectral combine; own lower Z' -> regs (yl), partner upper Z' -> partner slots
    cplx yl[4];
    {
        float sb, cb;
        __sincosf(-TWO_PI * (float)t * (1.0f / 8192.0f), &sb, &cb);
        cplx w0 = mkc(cb, sb);
        W16_TABLE
        cplx wk[4];
        wk[0] = w0;
        wk[1] = cmulv(w0, W16C1);
        wk[2] = cmulv(w0, W16C2);
        wk[3] = cmulv(w0, W16C3);
        const cplx* KfRow = Kf + (size_t)d * 4104;
        if (t == 0) {
            cplx z0 = zv[0];
            float U0 = z0.x + z0.y;
            float UN = z0.x - z0.y;
            float Y0 = U0 * KfRow[0].x;
            float YN = UN * KfRow[4096].x;
            yl[0] = mkc(0.5f * (Y0 + YN), 0.5f * (Y0 - YN));
            cplx zm = zv[4];                              // Z[2048]
            cplx Km = KfRow[2048];
            cplx Ym = cmuljv(zm, Km);                     // conj(Z)*K
            rp[544 * 4] = mkc(Ym.x, -Ym.y);               // Z'[2048]
#pragma unroll
            for (int i = 1; i < 4; i++) {
                cplx Zk = zv[i];
                cplx Zq = zv[8 - i];                      // own regs
                cplx K1 = KfRow[512 * i], K2 = KfRow[4096 - 512 * i];
                cplx Fe = 0.5f * (Zk + cconj(Zq));
                cplx Fo = 0.5f * (cnimul(Zk) + cswap(Zq));
                cplx WFo = cmulv(wk[i], Fo);
                cplx U1 = Fe + WFo;
                cplx U2 = cconj(Fe - WFo);
                cplx Y1 = cmulv(U1, K1);
                cplx Y2 = cmulv(U2, K2);
                cplx FeY = 0.5f * (Y1 + cconj(Y2));
                cplx Tv  = 0.5f * (Y1 - cconj(Y2));
                cplx FoY = cmuljv(wk[i], Tv);
                yl[i] = FeY + cimul(FoY);                 // Z'[512i]
                rp[544 * (8 - i)] = cconj(FeY - cimul(FoY)); // Z'[4096-512i]
            }
        } else {
            int p = 512 - t;
            cplx* pb = buf + (p + (p >> 4));
            const cplx* kfp = KfRow + t;
            const cplx* kfq = KfRow + (4096 - t);
#pragma unroll
            for (int i = 0; i < 4; i++) {
                cplx Zk = zv[i];
                cplx Zq = pb[544 * (7 - i)];              // partner's Z[4096-k]
                cplx K1 = kfp[512 * i], K2 = kfq[-512 * i];
                cplx Fe = 0.5f * (Zk + cconj(Zq));
                cplx Fo = 0.5f * (cnimul(Zk) + cswap(Zq));
                cplx WFo = cmulv(wk[i], Fo);
                cplx U1 = Fe + WFo;
                cplx U2 = cconj(Fe - WFo);
                cplx Y1 = cmulv(U1, K1);
                cplx Y2 = cmulv(U2, K2);
                cplx FeY = 0.5f * (Y1 + cconj(Y2));
                cplx Tv  = 0.5f * (Y1 - cconj(Y2));
                cplx FoY = cmuljv(wk[i], Tv);
                yl[i] = FeY + cimul(FoY);                 // Z'[t+512i]
                pb[544 * (7 - i)] = cconj(FeY - cimul(FoY)); // Z'[4096-k]
            }
        }
    }
    __syncthreads();                       // partner's Z' writes visible

    // read back own upper Z' (written by partner), then inverse pass 1 from regs
    cplx v[8];
#pragma unroll
    for (int i = 0; i < 4; i++) v[i] = yl[i];
#pragma unroll
    for (int s = 0; s < 4; s++) v[4 + s] = rp[544 * (4 + s)];
    __syncthreads();                       // all reads done before pass-1 writes
    dft8_pk<false>(v);
    {
        int b8 = 8 * t;
        cplx* wp = buf + (b8 + (b8 >> 4));
#pragma unroll
        for (int r = 0; r < 8; r++) wp[r] = v[r];
    }
    __syncthreads();
    fft_pass_ip<8, false>(buf, t);
    fft_pass_ip<64, false>(buf, t);

    // inverse last pass (NS=512) fused with the global store (only m<2048 needed)
    {
        cplx u[8];
#pragma unroll
        for (int r = 0; r < 8; r++) u[r] = rp[544 * r];
        cplx w[8];
        twiddle_powers(TWO_PI * (float)t * (1.0f / 4096.0f), w);
#pragma unroll
        for (int r = 1; r < 8; r++) u[r] = cmulv(u[r], w[r]);
        dft8_lo4_inv(u);
        float bd = bias[d];
        cplx* o2 = (cplx*)(out + (size_t)rid * 4096);
#pragma unroll
        for (int r = 0; r < 4; r++) {                    // m = t + r*512 < 2048
            o2[t + (r << 9)] = u[r] + bd * xv[r];
        }
    }
}

extern "C" void kernel_launch(void* const* d_in, const int* in_sizes, int n_in,
                              void* d_out, int out_size, void* d_ws, size_t ws_size,
                              hipStream_t stream) {
    const float* x      = (const float*)d_in[0];
    // d_in[1] = L (int scalar) — compile-time constant 4096 here
    const float* zin    = (const float*)d_in[2];
    const float* tvec   = (const float*)d_in[3];
    const float* deltas = (const float*)d_in[4];
    const float* W1     = (const float*)d_in[5];
    const float* b1     = (const float*)d_in[6];
    const float* freq   = (const float*)d_in[7];
    const float* W2     = (const float*)d_in[8];
    const float* b2     = (const float*)d_in[9];
    const float* W3     = (const float*)d_in[10];
    const float* b3     = (const float*)d_in[11];
    const float* W4     = (const float*)d_in[12];
    const float* bias   = (const float*)d_in[13];
    float* out = (float*)d_out;

    // ws layout: h3T (64 x 4096 f32 = 1 MB) | Kf (1024 rows * 4104 cplx = 33.6 MB)
    float* h3T = (float*)d_ws;
    cplx*  Kf  = (cplx*)((char*)d_ws + (size_t)64 * 4096 * sizeof(float));
    // k (1024x4096 f32 = 16 MB) staged in the tail of d_out (64 MB); conv
    // overwrites it afterwards (stream-ordered: kgemm -> filter_fft -> conv).
    float* kbuf = out + (size_t)3072 * 4096;

    mlp_kernel<<<64, 256, 0, stream>>>(zin, W1, b1, freq, W2, b2, W3, b3, h3T);
    kgemm_kernel<<<256, 256, 0, stream>>>(h3T, W4, tvec, deltas, kbuf);
    filter_fft_kernel<<<1024, 512, 0, stream>>>(kbuf, Kf);
    conv_kernel<<<4096, 512, 0, stream>>>(x, Kf, bias, out);
}

// Round 9
// 227.583 us; speedup vs baseline: 1.2199x; 1.0974x over previous
//
#include <hip/hip_runtime.h>
#include <math.h>

// Hyena filter: k = MLP(z)·decay ; out = irfft(rfft(x,8192)*rfft(k,8192))[:4096] + x*bias
// FFT: rfft(8192 real) via complex FFT of N=4096 (even/odd packing),
// radix-8 Stockham (4 passes), in-place in LDS.
// R6: strength-reduced LDS addressing (PAD identities), 1-sincos twiddle chains.
// R8: ext_vector(2) float complex arithmetic + shufflevector/fneg swizzles.
// FINAL (R12 = R8 revert): the probed alternatives all regressed —
//   radix-16 (R9, -12%: 256-thr blocks halve occupancy), global twiddle
//   tables (R10, -70%: table loads latency-stall every pass; sincos VALU
//   chains overlap instead), register-fused pass<512>/combine (R11, -22%:
//   +16 VGPR live across barriers collapses wave overlap, occ 73->39%).
//   This uniform low-live-state structure maximizes inter-wave overlap:
//   conv = 72.6us @ VALUBusy 71%, occ 73%, VGPR 28.

#define PAD(i) ((i) + ((i) >> 4))
#define TWO_PI 6.2831853071795864769f
#define C8 0.70710678118654752440f

typedef __attribute__((ext_vector_type(2))) float cplx;

static __device__ __forceinline__ cplx mkc(float x, float y) { cplx c; c.x = x; c.y = y; return c; }
static __device__ __forceinline__ cplx cswap(cplx v)  { return __builtin_shufflevector(v, v, 1, 0); }   // (y, x)
static __device__ __forceinline__ cplx cimul(cplx v)  { return __builtin_shufflevector(v, -v, 3, 0); }  // i*v  = (-y, x)
static __device__ __forceinline__ cplx cnimul(cplx v) { return __builtin_shufflevector(v, -v, 1, 2); }  // -i*v = (y, -x)
static __device__ __forceinline__ cplx cconj(cplx v)  { return __builtin_shufflevector(v, -v, 0, 3); }  // (x, -y)
static __device__ __forceinline__ cplx splx(cplx v)   { return __builtin_shufflevector(v, v, 0, 0); }
static __device__ __forceinline__ cplx sply(cplx v)   { return __builtin_shufflevector(v, v, 1, 1); }

// complex multiply a*b
static __device__ __forceinline__ cplx cmulv(cplx a, cplx b) {
    return splx(b) * a + sply(b) * cimul(a);
}
// conj(a)*b
static __device__ __forceinline__ cplx cmuljv(cplx a, cplx b) {
    return splx(a) * b + sply(a) * cnimul(b);
}

// 8-point DFT, natural order in/out. FWD: sgn=-1.
template <bool FWD>
__device__ __forceinline__ void dft8_pk(cplx v[8]) {
    const cplx w15 = FWD ? mkc(C8, -C8) : mkc(C8, C8);
    const cplx w37 = FWD ? mkc(-C8, -C8) : mkc(-C8, C8);
    cplx s0 = v[0] + v[4], s1 = v[0] - v[4];
    cplx s2 = v[2] + v[6], s3 = v[2] - v[6];
    cplx s4 = v[1] + v[5], s5 = v[1] - v[5];
    cplx s6 = v[3] + v[7], s7 = v[3] - v[7];
    cplx g0 = s0 + s2, g2 = s0 - s2;
    cplx g1 = FWD ? (s1 + cnimul(s3)) : (s1 + cimul(s3));
    cplx g3 = FWD ? (s1 + cimul(s3)) : (s1 + cnimul(s3));
    cplx g4 = s4 + s6, g6 = s4 - s6;
    cplx g5 = FWD ? (s5 + cnimul(s7)) : (s5 + cimul(s7));
    cplx g7 = FWD ? (s5 + cimul(s7)) : (s5 + cnimul(s7));
    v[0] = g0 + g4; v[4] = g0 - g4;
    cplx bt1 = cmulv(g5, w15);
    v[1] = g1 + bt1; v[5] = g1 - bt1;
    v[2] = FWD ? (g2 + cnimul(g6)) : (g2 + cimul(g6));
    v[6] = FWD ? (g2 + cimul(g6)) : (g2 + cnimul(g6));
    cplx bt3 = cmulv(g7, w37);
    v[3] = g3 + bt3; v[7] = g3 - bt3;
}

// inverse dft8 computing only v[0..3] (epilogue needs lower half only)
__device__ __forceinline__ void dft8_lo4_inv(cplx v[8]) {
    const cplx w15 = mkc(C8, C8), w37 = mkc(-C8, C8);
    cplx s0 = v[0] + v[4], s1 = v[0] - v[4];
    cplx s2 = v[2] + v[6], s3 = v[2] - v[6];
    cplx s4 = v[1] + v[5], s5 = v[1] - v[5];
    cplx s6 = v[3] + v[7], s7 = v[3] - v[7];
    cplx g0 = s0 + s2, g2 = s0 - s2;
    cplx g1 = s1 + cimul(s3), g3 = s1 + cnimul(s3);
    cplx g4 = s4 + s6, g6 = s4 - s6;
    cplx g5 = s5 + cimul(s7), g7 = s5 + cnimul(s7);
    v[0] = g0 + g4;
    v[1] = g1 + cmulv(g5, w15);
    v[2] = g2 + cimul(g6);
    v[3] = g3 + cmulv(g7, w37);
}

// Build w^1..w^7 from one sincos via shallow (depth<=3) cmul chains.
__device__ __forceinline__ void twiddle_powers(float ang, cplx w[8]) {
    float s, c;
    __sincosf(ang, &s, &c);
    w[1] = mkc(c, s);
    w[2] = cmulv(w[1], w[1]);
    w[3] = cmulv(w[2], w[1]);
    w[4] = cmulv(w[2], w[2]);
    w[5] = cmulv(w[4], w[1]);
    w[6] = cmulv(w[3], w[3]);
    w[7] = cmulv(w[4], w[3]);
}

// One Stockham radix-8 pass over N=4096 in LDS, in place. 512 threads, j = tid.
// Reads at PAD(j)+544r; writes at PAD(base)+{r | 8r+(r>>1) | 68r | 544r}.
template <int NS, bool FWD>
__device__ __forceinline__ void fft_pass_ip(cplx* __restrict__ buf, int j) {
    cplx* rp = buf + (j + (j >> 4));
    cplx v[8];
#pragma unroll
    for (int r = 0; r < 8; r++) v[r] = rp[544 * r];
    if (NS > 1) {
        int jm = j & (NS - 1);
        float ang = (FWD ? -1.0f : 1.0f) * (TWO_PI / (float)(NS * 8)) * (float)jm;
        cplx w[8];
        twiddle_powers(ang, w);
#pragma unroll
        for (int r = 1; r < 8; r++) v[r] = cmulv(v[r], w[r]);
    }
    dft8_pk<FWD>(v);
    __syncthreads();                       // everyone done reading
    int base = ((j & ~(NS - 1)) << 3) + (j & (NS - 1));
    cplx* wp = buf + (base + (base >> 4));
#pragma unroll
    for (int r = 0; r < 8; r++) {
        const int off = (NS == 1) ? r
                      : (NS == 8) ? (8 * r + (r >> 1))
                      : (NS == 64) ? (68 * r)
                      : (544 * r);
        wp[off] = v[r];
    }
    __syncthreads();
}

// Forward FFT pass 1 (NS=1) from registers; upper half zero, hand-folded.
__device__ __forceinline__ void fft_pass1_fwd_regs(cplx* __restrict__ buf, int j,
                                                   const cplx xv[4]) {
    const cplx w15 = mkc(C8, -C8), w37 = mkc(-C8, -C8);
    cplx a0 = xv[0] + xv[2], a2 = xv[0] - xv[2];
    cplx a1 = xv[0] + cnimul(xv[2]), a3 = xv[0] + cimul(xv[2]);
    cplx b0 = xv[1] + xv[3], b2 = xv[1] - xv[3];
    cplx b1 = xv[1] + cnimul(xv[3]), b3 = xv[1] + cimul(xv[3]);
    cplx v[8];
    v[0] = a0 + b0; v[4] = a0 - b0;
    cplx bt1 = cmulv(b1, w15);
    v[1] = a1 + bt1; v[5] = a1 - bt1;
    v[2] = a2 + cnimul(b2); v[6] = a2 + cimul(b2);
    cplx bt3 = cmulv(b3, w37);
    v[3] = a3 + bt3; v[7] = a3 - bt3;
    int b8 = 8 * j;
    cplx* wp = buf + (b8 + (b8 >> 4));
#pragma unroll
    for (int r = 0; r < 8; r++) wp[r] = v[r];
    __syncthreads();
}

// ---------------- Kernel 1: positional MLP -> h3T (64 x 4096) ----------------
__global__ __launch_bounds__(256) void mlp_kernel(
    const float* __restrict__ zin, const float* __restrict__ W1,
    const float* __restrict__ b1, const float* __restrict__ freq,
    const float* __restrict__ W2, const float* __restrict__ b2,
    const float* __restrict__ W3, const float* __restrict__ b3,
    float* __restrict__ h3T) {
    __shared__ float hs1[64][64];
    __shared__ float hs2[64][64];
    int tid = threadIdx.x;
    int l = tid & 63, w = tid >> 6;
    int lg = blockIdx.x * 64 + l;          // grid = 64 blocks covers 4096

    float zf[5];
#pragma unroll
    for (int e = 0; e < 5; e++) zf[e] = zin[lg * 5 + e];

    // layer 1
#pragma unroll
    for (int i = 0; i < 16; i++) {
        int o = w * 16 + i;
        float a = b1[o];
#pragma unroll
        for (int e = 0; e < 5; e++) a += W1[o * 5 + e] * zf[e];
        hs1[o][l] = __sinf(freq[o] * a);
    }
    __syncthreads();

    // layer 2
    float acc[16];
#pragma unroll
    for (int i = 0; i < 16; i++) acc[i] = b2[w * 16 + i];
#pragma unroll 8
    for (int o = 0; o < 64; o++) {
        float hv = hs1[o][l];
#pragma unroll
        for (int i = 0; i < 16; i++) acc[i] += W2[(w * 16 + i) * 64 + o] * hv;
    }
#pragma unroll
    for (int i = 0; i < 16; i++)
        hs2[w * 16 + i][l] = __sinf(freq[w * 16 + i] * acc[i]);
    __syncthreads();

    // layer 3
#pragma unroll
    for (int i = 0; i < 16; i++) acc[i] = b3[w * 16 + i];
#pragma unroll 8
    for (int o = 0; o < 64; o++) {
        float hv = hs2[o][l];
#pragma unroll
        for (int i = 0; i < 16; i++) acc[i] += W3[(w * 16 + i) * 64 + o] * hv;
    }
#pragma unroll
    for (int i = 0; i < 16; i++)
        h3T[(size_t)(w * 16 + i) * 4096 + lg] = __sinf(freq[w * 16 + i] * acc[i]);
}

// -------- Kernel 2: k[d,l] = <h3[:,l], W4[d,:]> * exp(-t[l]*|delta[d]|) --------
__global__ __launch_bounds__(256) void kgemm_kernel(
    const float* __restrict__ h3T, const float* __restrict__ W4,
    const float* __restrict__ tvec, const float* __restrict__ deltas,
    float* __restrict__ kout) {
    int lt = blockIdx.x & 3;       // l tile (4 x 1024)
    int dt = blockIdx.x >> 2;      // d tile (64 x 16)
    int l0 = lt * 1024 + threadIdx.x * 4;
    float4 acc[16];
#pragma unroll
    for (int i = 0; i < 16; i++) acc[i] = make_float4(0.f, 0.f, 0.f, 0.f);
#pragma unroll 8
    for (int o = 0; o < 64; o++) {
        float4 h = *(const float4*)(h3T + (size_t)o * 4096 + l0);
#pragma unroll
        for (int i = 0; i < 16; i++) {
            float wv = W4[(size_t)(dt * 16 + i) * 64 + o];
            acc[i].x += wv * h.x; acc[i].y += wv * h.y;
            acc[i].z += wv * h.z; acc[i].w += wv * h.w;
        }
    }
    float4 tl = *(const float4*)(tvec + l0);
#pragma unroll
    for (int i = 0; i < 16; i++) {
        int d = dt * 16 + i;
        float da = fabsf(deltas[d]);
        float4 o;
        o.x = acc[i].x * __expf(-tl.x * da);
        o.y = acc[i].y * __expf(-tl.y * da);
        o.z = acc[i].z * __expf(-tl.z * da);
        o.w = acc[i].w * __expf(-tl.w * da);
        *(float4*)(kout + (size_t)d * 4096 + l0) = o;
    }
}

// ------- Kernel 3: per-channel rfft(k,8192) -> Kf[d][0..4096] -------
// Kf stored with 1/4096 inverse-FFT scale folded in. Row stride 4104 complexes.
__global__ __launch_bounds__(512) void filter_fft_kernel(
    const float* __restrict__ kin, cplx* __restrict__ Kf) {
    __shared__ cplx buf[4352];
    int d = blockIdx.x, t = threadIdx.x;

    const cplx* k2 = (const cplx*)(kin + (size_t)d * 4096);
    cplx xv[4];
#pragma unroll
    for (int r = 0; r < 4; r++) xv[r] = k2[t + (r << 9)];
    fft_pass1_fwd_regs(buf, t, xv);
    fft_pass_ip<8, true>(buf, t);
    fft_pass_ip<64, true>(buf, t);
    fft_pass_ip<512, true>(buf, t);

    const float scale = 1.0f / 4096.0f;
    // W8192^(t + 512 i) = W8192^t * W16^i ; W16^i compile-time.
    float sb, cb;
    __sincosf(-TWO_PI * (float)t * (1.0f / 8192.0f), &sb, &cb);
    cplx wk[4];
    wk[0] = mkc(cb, sb);
    wk[1] = cmulv(wk[0], mkc(0.92387953251128675613f, -0.38268343236508977173f));
    wk[2] = cmulv(wk[0], mkc(0.70710678118654752440f, -0.70710678118654752440f));
    wk[3] = cmulv(wk[0], mkc(0.38268343236508977173f, -0.92387953251128675613f));

    cplx* rb  = buf + (t + (t >> 4));
    cplx* qb2 = buf + (((4096 - t) + ((4096 - t) >> 4)) - 1632);
    cplx* KfRow = Kf + (size_t)d * 4104;
    cplx* kfp = KfRow + t;                 // + 512 i
    cplx* kfq = KfRow + (4096 - t);        // - 512 i
#pragma unroll
    for (int i = 0; i < 4; i++) {
        if (t == 0 && i == 0) {            // bins 0, 4096, 2048 (thread 0 only)
            cplx z0 = buf[0];              // PAD(0)=0
            KfRow[0]    = mkc((z0.x + z0.y) * scale, 0.f);
            KfRow[4096] = mkc((z0.x - z0.y) * scale, 0.f);
            cplx zm = buf[PAD(2048)];
            KfRow[2048] = mkc(zm.x * scale, -zm.y * scale);
        } else {
            cplx Zk = rb[544 * i];
            cplx Zq = qb2[544 * (3 - i)];
            cplx Fe = 0.5f * (Zk + cconj(Zq));            // (Zk.x+Zq.x, Zk.y-Zq.y)/2
            cplx Fo = 0.5f * (cnimul(Zk) + cswap(Zq));    // (Zk.y+Zq.y, Zq.x-Zk.x)/2
            cplx WFo = cmulv(wk[i], Fo);
            kfp[512 * i]  = scale * (Fe + WFo);
            kfq[-512 * i] = scale * cconj(Fe - WFo);
        }
    }
}

// ------- Kernel 4: per (b,d) row: FFT -> spectral multiply -> IFFT -> +x*bias -------
__global__ __launch_bounds__(512) void conv_kernel(
    const float* __restrict__ x, const cplx* __restrict__ Kf,
    const float* __restrict__ bias, float* __restrict__ out) {
    __shared__ cplx buf[4352];
    int rid = blockIdx.x;          // rid = b*1024 + d
    int d = rid & 1023;
    int t = threadIdx.x;

    const cplx* x2 = (const cplx*)(x + (size_t)rid * 4096);
    cplx xv[4];
#pragma unroll
    for (int r = 0; r < 4; r++) xv[r] = x2[t + (r << 9)];
    fft_pass1_fwd_regs(buf, t, xv);
    fft_pass_ip<8, true>(buf, t);
    fft_pass_ip<64, true>(buf, t);
    fft_pass_ip<512, true>(buf, t);

    // spectral combine: each (k, 4096-k) pair owned by one thread -> in-place
    float sb, cb;
    __sincosf(-TWO_PI * (float)t * (1.0f / 8192.0f), &sb, &cb);
    cplx wk[4];
    wk[0] = mkc(cb, sb);
    wk[1] = cmulv(wk[0], mkc(0.92387953251128675613f, -0.38268343236508977173f));
    wk[2] = cmulv(wk[0], mkc(0.70710678118654752440f, -0.70710678118654752440f));
    wk[3] = cmulv(wk[0], mkc(0.38268343236508977173f, -0.92387953251128675613f));

    cplx* rb  = buf + (t + (t >> 4));
    cplx* qb2 = buf + (((4096 - t) + ((4096 - t) >> 4)) - 1632);
    const cplx* KfRow = Kf + (size_t)d * 4104;
    const cplx* kfp = KfRow + t;
    const cplx* kfq = KfRow + (4096 - t);
#pragma unroll
    for (int i = 0; i < 4; i++) {
        if (t == 0 && i == 0) {
            cplx z0 = buf[0];
            float U0 = z0.x + z0.y;
            float UN = z0.x - z0.y;
            float Y0 = U0 * KfRow[0].x;
            float YN = UN * KfRow[4096].x;
            buf[0] = mkc(0.5f * (Y0 + YN), 0.5f * (Y0 - YN));
            cplx zm = buf[PAD(2048)];
            cplx Km = KfRow[2048];
            // Y = conj(Z[2048]) * K ; store conj(Y)
            cplx Ym = mkc(zm.x * Km.x + zm.y * Km.y, zm.x * Km.y - zm.y * Km.x);
            buf[PAD(2048)] = mkc(Ym.x, -Ym.y);
        } else {
            cplx Zk = rb[544 * i];
            cplx Zq = qb2[544 * (3 - i)];
            cplx K1 = kfp[512 * i], K2 = kfq[-512 * i];
            cplx Fe = 0.5f * (Zk + cconj(Zq));
            cplx Fo = 0.5f * (cnimul(Zk) + cswap(Zq));
            cplx WFo = cmulv(wk[i], Fo);
            cplx U1 = Fe + WFo;
            cplx U2 = cconj(Fe - WFo);
            cplx Y1 = cmulv(U1, K1);
            cplx Y2 = cmulv(U2, K2);
            cplx FeY = 0.5f * (Y1 + cconj(Y2));
            cplx T   = 0.5f * (Y1 - cconj(Y2));
            cplx FoY = cmuljv(wk[i], T);                 // conj(wk) * T
            rb[544 * i]        = FeY + cimul(FoY);
            qb2[544 * (3 - i)] = cconj(FeY - cimul(FoY));
        }
    }
    __syncthreads();

    // inverse FFT; last pass fused with the global store (only m<2048 needed)
    fft_pass_ip<1, false>(buf, t);
    fft_pass_ip<8, false>(buf, t);
    fft_pass_ip<64, false>(buf, t);
    {
        cplx v[8];
#pragma unroll
        for (int r = 0; r < 8; r++) v[r] = rb[544 * r];
        float ang = (TWO_PI / 4096.0f) * (float)t;       // inverse, NS=512
        cplx w[8];
        twiddle_powers(ang, w);
#pragma unroll
        for (int r = 1; r < 8; r++) v[r] = cmulv(v[r], w[r]);
        dft8_lo4_inv(v);
        float bd = bias[d];
        cplx* o2 = (cplx*)(out + (size_t)rid * 4096);
#pragma unroll
        for (int r = 0; r < 4; r++) {                    // m = t + r*512 < 2048
            o2[t + (r << 9)] = v[r] + bd * xv[r];
        }
    }
}

extern "C" void kernel_launch(void* const* d_in, const int* in_sizes, int n_in,
                              void* d_out, int out_size, void* d_ws, size_t ws_size,
                              hipStream_t stream) {
    const float* x      = (const float*)d_in[0];
    // d_in[1] = L (int scalar) — compile-time constant 4096 here
    const float* zin    = (const float*)d_in[2];
    const float* tvec   = (const float*)d_in[3];
    const float* deltas = (const float*)d_in[4];
    const float* W1     = (const float*)d_in[5];
    const float* b1     = (const float*)d_in[6];
    const float* freq   = (const float*)d_in[7];
    const float* W2     = (const float*)d_in[8];
    const float* b2     = (const float*)d_in[9];
    const float* W3     = (const float*)d_in[10];
    const float* b3     = (const float*)d_in[11];
    const float* W4     = (const float*)d_in[12];
    const float* bias   = (const float*)d_in[13];
    float* out = (float*)d_out;

    // ws layout: h3T (64 x 4096 f32 = 1 MB) | Kf (1024 rows * 4104 cplx = 33.6 MB)
    float* h3T = (float*)d_ws;
    cplx*  Kf  = (cplx*)((char*)d_ws + (size_t)64 * 4096 * sizeof(float));
    // k (1024x4096 f32 = 16 MB) staged in the tail of d_out (64 MB); conv
    // overwrites it afterwards (stream-ordered: kgemm -> filter_fft -> conv).
    float* kbuf = out + (size_t)3072 * 4096;

    mlp_kernel<<<64, 256, 0, stream>>>(zin, W1, b1, freq, W2, b2, W3, b3, h3T);
    kgemm_kernel<<<256, 256, 0, stream>>>(h3T, W4, tvec, deltas, kbuf);
    filter_fft_kernel<<<1024, 512, 0, stream>>>(kbuf, Kf);
    conv_kernel<<<4096, 512, 0, stream>>>(x, Kf, bias, out);
}